// Round 12
// baseline (336.503 us; speedup 1.0000x reference)
//
#include <hip/hip_runtime.h>
#include <math.h>

#define E_NUM 320000
#define N_NUM 10000
#define NB8   (N_NUM / 8)           // 1250 blocks (embed)
#define NB16  (N_NUM / 16)          // 625 blocks (layer)
#define TAB   2048

typedef unsigned short ushort_t;
typedef short short8_t __attribute__((ext_vector_type(8)));   // 8 bf16 (4 VGPRs)
typedef float f32x4    __attribute__((ext_vector_type(4)));   // MFMA acc

// wpack layout (shorts):
//   [0)        6x lin2_w  128x128
//   [98304)    6x lin_w   128x128
//   [196608)   6x lin1_w  128x128
//   [294912)   o1w 128x64
//   [303104)   o2w 64x64
//   [307200)   6x mlp_w1  (K=64 zero-padded)x128  -> 8192 each
//   [356352)   6x mlp_w2  128x128                 -> 16384 each
#define WP_O1   294912
#define WP_O2   303104
#define WP_W1T  307200
#define WP_W2T  356352
#define WP_TOT  454656

__device__ __forceinline__ float ssp_f(float x) {
    return fmaxf(x, 0.f) + __logf(1.f + __expf(-fabsf(x))) - 0.69314718056f;
}

__device__ __forceinline__ float bf2f(ushort_t u) {
    union { unsigned int i; float f; } v;
    v.i = ((unsigned int)u) << 16;
    return v.f;
}
__device__ __forceinline__ ushort_t f2bf(float f) {
    union { float f; unsigned int i; } v;
    v.f = f;
    unsigned int u = v.i;
    unsigned int r = (u + 0x7FFFu + ((u >> 16) & 1u)) >> 16;   // RNE
    return (ushort_t)r;
}

// ---------------------------------------------------------------------------
// counting-sort phase 1: histogram of dst
__global__ __launch_bounds__(256) void hist_kernel(const int* __restrict__ ei,
                                                   int* __restrict__ counts) {
    int e = blockIdx.x * 256 + threadIdx.x;
    if (e < E_NUM) atomicAdd(&counts[ei[E_NUM + e]], 1);
}

// phase 2: exclusive scan over 10000 bins (single block)
__global__ __launch_bounds__(256) void scan_kernel(const int* __restrict__ counts,
                                                   int* __restrict__ offs,
                                                   int* __restrict__ cursor) {
    __shared__ int part[256];
    const int tid = threadIdx.x;
    const int CH = 40;
    int base = tid * CH;
    int s = 0;
    for (int i = 0; i < CH; ++i) {
        int idx = base + i;
        if (idx < N_NUM) s += counts[idx];
    }
    part[tid] = s;
    __syncthreads();
    for (int off = 1; off < 256; off <<= 1) {
        int v = (tid >= off) ? part[tid - off] : 0;
        __syncthreads();
        part[tid] += v;
        __syncthreads();
    }
    int run = (tid > 0) ? part[tid - 1] : 0;
    for (int i = 0; i < CH; ++i) {
        int idx = base + i;
        if (idx < N_NUM) {
            offs[idx] = run;
            cursor[idx] = run;
            run += counts[idx];
        }
    }
    if (tid == 255) offs[N_NUM] = part[255];
}

// phase 3: scatter edges to dst-sorted order.
// meta = (i0 << 14) | src ; i0 = nearest table row (11 bits), src 14 bits.
__global__ __launch_bounds__(256) void scatter_kernel(const int* __restrict__ ei,
                                                      const float* __restrict__ dist,
                                                      int* __restrict__ cursor,
                                                      int* __restrict__ meta) {
    int e = blockIdx.x * 256 + threadIdx.x;
    if (e >= E_NUM) return;
    int d = ei[E_NUM + e];
    int pos = atomicAdd(&cursor[d], 1);
    float t = dist[e] * ((float)(TAB - 1) / 10.0f);
    int i0 = (int)(t + 0.5f);
    if (i0 > TAB - 1) i0 = TAB - 1;
    meta[pos] = (i0 << 14) | ei[e];
}

// phase 4: degree-balanced node permutation (descending degree).
// nodeperm[rank] = node id; consecutive ranks have near-equal degree, so the
// 4 quarter-wave streams of each wave are balanced (divergence waste -> ~0).
__global__ __launch_bounds__(256) void degsort_kernel(const int* __restrict__ counts,
                                                      int* __restrict__ nodeperm) {
    __shared__ int dh[256];
    __shared__ int db[256];
    const int tid = threadIdx.x;
    dh[tid] = 0;
    __syncthreads();
    for (int n = tid; n < N_NUM; n += 256) {
        int d = counts[n]; if (d > 255) d = 255;
        atomicAdd(&dh[255 - d], 1);   // bin 0 = highest degree
    }
    __syncthreads();
    int own = dh[tid];
    for (int off = 1; off < 256; off <<= 1) {
        int v = (tid >= off) ? dh[tid - off] : 0;
        __syncthreads();
        dh[tid] += v;
        __syncthreads();
    }
    db[tid] = dh[tid] - own;          // exclusive prefix = bin base
    __syncthreads();
    for (int n = tid; n < N_NUM; n += 256) {
        int d = counts[n]; if (d > 255) d = 255;
        int pos = atomicAdd(&db[255 - d], 1);
        nodeperm[pos] = n;
    }
}

// ---------------------------------------------------------------------------
// Pack all weights into MFMA B-fragment order (bf16).
// B-frag: idx = ((t*KSP + ks)*64 + L)*8 + j ; n = t*16+(L&15), k = ks*32+(L>>4)*8+j
__global__ __launch_bounds__(256) void pack_kernel(const float* __restrict__ lin2_w,
                                                   const float* __restrict__ lin_w,
                                                   const float* __restrict__ lin1_w,
                                                   const float* __restrict__ o1w,
                                                   const float* __restrict__ o2w,
                                                   const float* __restrict__ mlp_w1,
                                                   const float* __restrict__ mlp_w2,
                                                   short* __restrict__ wpack) {
    int idx = blockIdx.x * 256 + threadIdx.x;
    const int M128 = 16384;
    if (idx < 18 * M128) {
        int g = idx / M128, r = idx % M128;
        const float* src;
        if (g < 6) src = lin2_w + g * M128;
        else if (g < 12) src = lin_w + (g - 6) * M128;
        else src = lin1_w + (g - 12) * M128;
        int j = r & 7, L = (r >> 3) & 63, ks = (r >> 9) & 3, t = r >> 11;
        int n = t * 16 + (L & 15);
        int k = ks * 32 + (L >> 4) * 8 + j;
        wpack[idx] = (short)f2bf(src[k * 128 + n]);
    } else if (idx < WP_O2) {
        int r = idx - WP_O1;              // o1w: K=128, N=64
        int j = r & 7, L = (r >> 3) & 63, ks = (r >> 9) & 3, t = r >> 11;
        int n = t * 16 + (L & 15);
        int k = ks * 32 + (L >> 4) * 8 + j;
        wpack[idx] = (short)f2bf(o1w[k * 64 + n]);
    } else if (idx < WP_W1T) {
        int r = idx - WP_O2;              // o2w: K=64, N=64
        int j = r & 7, L = (r >> 3) & 63, ks = (r >> 9) & 1, t = r >> 10;
        int n = t * 16 + (L & 15);
        int k = ks * 32 + (L >> 4) * 8 + j;
        wpack[idx] = (short)f2bf(o2w[k * 64 + n]);
    } else if (idx < WP_W2T) {
        int r2 = idx - WP_W1T;            // mlp_w1: K=50 pad to 64, N=128
        int g = r2 / 8192, r = r2 % 8192;
        int j = r & 7, L = (r >> 3) & 63, ks = (r >> 9) & 1, t = r >> 10;
        int n = t * 16 + (L & 15);
        int k = ks * 32 + (L >> 4) * 8 + j;
        float v = (k < 50) ? mlp_w1[g * 6400 + k * 128 + n] : 0.f;
        wpack[idx] = (short)f2bf(v);
    } else if (idx < WP_TOT) {
        int r2 = idx - WP_W2T;            // mlp_w2: K=128, N=128
        int g = r2 / M128, r = r2 % M128;
        int j = r & 7, L = (r >> 3) & 63, ks = (r >> 9) & 3, t = r >> 11;
        int n = t * 16 + (L & 15);
        int k = ks * 32 + (L >> 4) * 8 + j;
        wpack[idx] = (short)f2bf(mlp_w2[g * M128 + k * 128 + n]);
    }
}

// ---------------------------------------------------------------------------
// MFMA table build: plain row layout tab[l][i][c] (bf16), nearest-neighbor use.
// 16 d-rows/block, 512 threads, 6*(TAB/16) = 768 blocks.
__global__ __launch_bounds__(512) void table_kernel(const short* __restrict__ w1t,
                                                    const float* __restrict__ mlp_b1,
                                                    const short* __restrict__ w2t,
                                                    const float* __restrict__ mlp_b2,
                                                    ushort_t* __restrict__ tabB) {
    __shared__ short EA[16 * 72];    // bf16 gaussians, K padded to 64
    __shared__ short HD[16 * 136];   // bf16 hidden
    const int tid = threadIdx.x;
    const int wv = tid >> 6;
    const int lane = tid & 63;
    const int l = blockIdx.x >> 7;              // / (TAB/16 = 128)
    const int r0 = (blockIdx.x & 127) * 16;
    const float DG = 10.0f / (float)(TAB - 1);
    const float STEP = 10.0f / 49.0f;
    const float COEFF = -0.5f / (STEP * STEP);

    for (int i = tid; i < 16 * 64; i += 512) {
        int r = i >> 6, k = i & 63;
        float v = 0.f;
        if (k < 50) {
            float d = (float)(r0 + r) * DG;
            float t = d - (float)k * STEP;
            v = __expf(COEFF * t * t);
        }
        EA[r * 72 + k] = (short)f2bf(v);
    }
    __syncthreads();

    const int m = lane & 15, q = lane >> 4;

    // stage 1: hidden = ssp(ea @ w1 + b1), K=64 (padded)
    {
        f32x4 acc = {0.f, 0.f, 0.f, 0.f};
        #pragma unroll
        for (int ks = 0; ks < 2; ++ks) {
            short8_t a = *(const short8_t*)(EA + m * 72 + ks * 32 + q * 8);
            short8_t b = *(const short8_t*)(w1t + l * 8192 + (wv * 2 + ks) * 512 + lane * 8);
            acc = __builtin_amdgcn_mfma_f32_16x16x32_bf16(a, b, acc, 0, 0, 0);
        }
        float bv = mlp_b1[l * 128 + wv * 16 + m];
        #pragma unroll
        for (int i = 0; i < 4; ++i)
            HD[(q * 4 + i) * 136 + wv * 16 + m] = (short)f2bf(ssp_f(acc[i] + bv));
    }
    __syncthreads();

    // stage 2: W = hidden @ w2 + b2, *C(d), plain row write
    {
        f32x4 acc = {0.f, 0.f, 0.f, 0.f};
        #pragma unroll
        for (int ks = 0; ks < 4; ++ks) {
            short8_t a = *(const short8_t*)(HD + m * 136 + ks * 32 + q * 8);
            short8_t b = *(const short8_t*)(w2t + l * 16384 + (wv * 4 + ks) * 512 + lane * 8);
            acc = __builtin_amdgcn_mfma_f32_16x16x32_bf16(a, b, acc, 0, 0, 0);
        }
        int col = wv * 16 + m;
        float bv = mlp_b2[l * 128 + col];
        ushort_t* tl = tabB + (size_t)l * TAB * 128;
        #pragma unroll
        for (int i = 0; i < 4; ++i) {
            int row = r0 + q * 4 + i;
            float d = (float)row * DG;
            float C = 0.5f * (__cosf(d * 0.31415926535f) + 1.0f);
            tl[(size_t)row * 128 + col] = f2bf((acc[i] + bv) * C);
        }
    }
}

// ---------------------------------------------------------------------------
// nearest-neighbor accumulate: 8 cols/lane, one edge
__device__ __forceinline__ void nacc8(short8_t x, short8_t t, float* o) {
    #pragma unroll
    for (int j = 0; j < 8; ++j)
        o[j] = fmaf(bf2f((ushort_t)x[j]), bf2f((ushort_t)t[j]), o[j]);
}

// ---------------------------------------------------------------------------
// Layer 0 front: h = emb[x]; xf = bf16(h @ lin1_w[0]).  8 rows/block, 256 thr.
__global__ __launch_bounds__(256) void embed_lin1_kernel(const int* __restrict__ x,
                                                         const float* __restrict__ emb,
                                                         const float* __restrict__ B,
                                                         float* __restrict__ h,
                                                         ushort_t* __restrict__ xf) {
    __shared__ float AT[128][9];
    __shared__ int s_x[8];
    const int tid = threadIdx.x;
    const int n0 = blockIdx.x * 8;

    if (tid < 8) s_x[tid] = x[n0 + tid];
    __syncthreads();
    for (int i = tid; i < 8 * 128; i += 256) {
        int r = i >> 7, c = i & 127;
        float v = emb[s_x[r] * 128 + c];
        AT[c][r] = v;
        h[(size_t)(n0 + r) * 128 + c] = v;
    }
    __syncthreads();

    const int r  = tid & 7;
    const int c0 = (tid >> 3) * 4;
    float acc[4] = {0.f, 0.f, 0.f, 0.f};
    for (int k = 0; k < 128; k += 4) {
        float a[4];
        #pragma unroll
        for (int u = 0; u < 4; ++u) a[u] = AT[k + u][r];
        #pragma unroll
        for (int u = 0; u < 4; ++u) {
            float4 b = *(const float4*)(B + (size_t)(k + u) * 128 + c0);
            acc[0] = fmaf(a[u], b.x, acc[0]);
            acc[1] = fmaf(a[u], b.y, acc[1]);
            acc[2] = fmaf(a[u], b.z, acc[2]);
            acc[3] = fmaf(a[u], b.w, acc[3]);
        }
    }
    ushort4 o;
    o.x = f2bf(acc[0]); o.y = f2bf(acc[1]); o.z = f2bf(acc[2]); o.w = f2bf(acc[3]);
    *(ushort4*)(xf + (size_t)(n0 + r) * 128 + c0) = o;
}

// ---------------------------------------------------------------------------
// MFMA stage helper: wave computes two 16-col tiles t0,t1.
__device__ __forceinline__ void mfma_stage2(const short* A_lds, const short* wp,
                                            int lane, int t0, int t1,
                                            f32x4& acc0, f32x4& acc1) {
    const int m = lane & 15, q = lane >> 4;
    #pragma unroll
    for (int ks = 0; ks < 4; ++ks) {
        short8_t a  = *(const short8_t*)(A_lds + m * 136 + ks * 32 + q * 8);
        short8_t b0 = *(const short8_t*)(wp + (t0 * 4 + ks) * 512 + lane * 8);
        short8_t b1 = *(const short8_t*)(wp + (t1 * 4 + ks) * 512 + lane * 8);
        acc0 = __builtin_amdgcn_mfma_f32_16x16x32_bf16(a, b0, acc0, 0, 0, 0);
        acc1 = __builtin_amdgcn_mfma_f32_16x16x32_bf16(a, b1, acc1, 0, 0, 0);
    }
}

// ---------------------------------------------------------------------------
// Fused MFMA layer kernel: 16 nodes/block (degree-balanced via nodeperm),
// 256 threads (4 waves). phase A: quarter-wave edge streams (16 lanes x 8
// cols, 16B/lane loads; one wave instr serves 4 edges). Streams in a wave
// have near-equal degree by construction -> minimal divergence waste.
// MFMA stages: wave wv computes col-tiles wv*2, wv*2+1.
template <bool LAST>
__global__ __launch_bounds__(256) void layer_kernel(const int* __restrict__ offs,
                                                    const int* __restrict__ nodeperm,
                                                    const int* __restrict__ meta,
                                                    const ushort_t* __restrict__ xf,
                                                    const ushort_t* __restrict__ tabB,
                                                    const short* __restrict__ w2p,
                                                    const float* __restrict__ lin2_b,
                                                    const short* __restrict__ wlp,
                                                    const float* __restrict__ lin_b,
                                                    const short* __restrict__ w1p,
                                                    float* __restrict__ h,
                                                    ushort_t* __restrict__ xf_out,
                                                    const short* __restrict__ o1p,
                                                    const float* __restrict__ o1b,
                                                    const short* __restrict__ o2p,
                                                    const float* __restrict__ o2b,
                                                    float* __restrict__ gs) {
    __shared__ short A1[16 * 136];   // bf16, row stride 136 shorts (272 B)
    __shared__ short A2[16 * 136];
    __shared__ float red[4][64];
    __shared__ int s_nid[16];
    const int tid = threadIdx.x;
    const int n0 = blockIdx.x * 16;
    const int wv = tid >> 6;         // 0..3
    const int lane = tid & 63;

    if (tid < 16) s_nid[tid] = nodeperm[n0 + tid];
    __syncthreads();

    // ---- phase A: quarter-wave edge streams, nearest table row ----
    {
        const int qt = lane >> 4;        // 0..3
        const int c8 = (lane & 15) * 8;  // 8 cols/lane
        const int node = s_nid[wv * 4 + qt];
        int e   = offs[node];
        int end = offs[node + 1];

        float accA[8] = {0.f, 0.f, 0.f, 0.f, 0.f, 0.f, 0.f, 0.f};
        float accB[8] = {0.f, 0.f, 0.f, 0.f, 0.f, 0.f, 0.f, 0.f};

        for (; e + 8 <= end; e += 8) {
            int m[8];
            #pragma unroll
            for (int u = 0; u < 8; ++u) m[u] = meta[e + u];
            short8_t xv[8], tv[8];
            #pragma unroll
            for (int u = 0; u < 8; ++u) {
                xv[u] = *(const short8_t*)(xf + (size_t)(m[u] & 0x3FFF) * 128 + c8);
                tv[u] = *(const short8_t*)(tabB + (size_t)((unsigned)m[u] >> 14) * 128 + c8);
            }
            #pragma unroll
            for (int u = 0; u < 8; ++u)
                nacc8(xv[u], tv[u], (u & 1) ? accB : accA);
        }
        for (; e + 4 <= end; e += 4) {
            int m[4];
            #pragma unroll
            for (int u = 0; u < 4; ++u) m[u] = meta[e + u];
            short8_t xv[4], tv[4];
            #pragma unroll
            for (int u = 0; u < 4; ++u) {
                xv[u] = *(const short8_t*)(xf + (size_t)(m[u] & 0x3FFF) * 128 + c8);
                tv[u] = *(const short8_t*)(tabB + (size_t)((unsigned)m[u] >> 14) * 128 + c8);
            }
            #pragma unroll
            for (int u = 0; u < 4; ++u)
                nacc8(xv[u], tv[u], (u & 1) ? accB : accA);
        }
        for (; e < end; ++e) {
            int mm = meta[e];
            short8_t xv = *(const short8_t*)(xf + (size_t)(mm & 0x3FFF) * 128 + c8);
            short8_t tv = *(const short8_t*)(tabB + (size_t)((unsigned)mm >> 14) * 128 + c8);
            nacc8(xv, tv, accA);
        }

        short8_t out;
        #pragma unroll
        for (int j = 0; j < 8; ++j) out[j] = (short)f2bf(accA[j] + accB[j]);
        *(short8_t*)&A1[(wv * 4 + qt) * 136 + c8] = out;
    }
    __syncthreads();

    const int m = lane & 15, q = lane >> 4;
    const int t0 = wv * 2, t1 = wv * 2 + 1;

    // ---- stage 1: t = ssp(agg @ lin2_w + lin2_b) -> A2 ----
    {
        f32x4 acc0 = {0.f, 0.f, 0.f, 0.f}, acc1 = {0.f, 0.f, 0.f, 0.f};
        mfma_stage2(A1, w2p, lane, t0, t1, acc0, acc1);
        float bv0 = lin2_b[t0 * 16 + m];
        float bv1 = lin2_b[t1 * 16 + m];
        #pragma unroll
        for (int i = 0; i < 4; ++i) {
            int r = q * 4 + i;
            A2[r * 136 + t0 * 16 + m] = (short)f2bf(ssp_f(acc0[i] + bv0));
            A2[r * 136 + t1 * 16 + m] = (short)f2bf(ssp_f(acc1[i] + bv1));
        }
    }
    __syncthreads();

    // ---- stage 2: h_new = h + t @ lin_w + lin_b -> A1 (+ global h if !LAST) ----
    {
        f32x4 acc0 = {0.f, 0.f, 0.f, 0.f}, acc1 = {0.f, 0.f, 0.f, 0.f};
        mfma_stage2(A2, wlp, lane, t0, t1, acc0, acc1);
        float bv0 = lin_b[t0 * 16 + m];
        float bv1 = lin_b[t1 * 16 + m];
        #pragma unroll
        for (int i = 0; i < 4; ++i) {
            int r = q * 4 + i;
            int nid = s_nid[r];
            float h0 = h[(size_t)nid * 128 + t0 * 16 + m];
            float h1 = h[(size_t)nid * 128 + t1 * 16 + m];
            float hn0 = h0 + acc0[i] + bv0;
            float hn1 = h1 + acc1[i] + bv1;
            if (!LAST) {
                h[(size_t)nid * 128 + t0 * 16 + m] = hn0;
                h[(size_t)nid * 128 + t1 * 16 + m] = hn1;
            }
            A1[r * 136 + t0 * 16 + m] = (short)f2bf(hn0);
            A1[r * 136 + t1 * 16 + m] = (short)f2bf(hn1);
        }
    }
    __syncthreads();

    if constexpr (!LAST) {
        // ---- stage 3: xf_out = bf16(h_new @ lin1_next) ----
        f32x4 acc0 = {0.f, 0.f, 0.f, 0.f}, acc1 = {0.f, 0.f, 0.f, 0.f};
        mfma_stage2(A1, w1p, lane, t0, t1, acc0, acc1);
        #pragma unroll
        for (int i = 0; i < 4; ++i) {
            int r = q * 4 + i;
            int nid = s_nid[r];
            xf_out[(size_t)nid * 128 + t0 * 16 + m] = f2bf(acc0[i]);
            xf_out[(size_t)nid * 128 + t1 * 16 + m] = f2bf(acc1[i]);
        }
    } else {
        // ---- fused head: t1 = ssp(h_new@o1w+o1b); t2 = t1@o2w+o2b; colsum ----
        {
            f32x4 acc = {0.f, 0.f, 0.f, 0.f};
            #pragma unroll
            for (int ks = 0; ks < 4; ++ks) {
                short8_t a = *(const short8_t*)(A1 + m * 136 + ks * 32 + q * 8);
                short8_t b = *(const short8_t*)(o1p + (wv * 4 + ks) * 512 + lane * 8);
                acc = __builtin_amdgcn_mfma_f32_16x16x32_bf16(a, b, acc, 0, 0, 0);
            }
            float bv = o1b[wv * 16 + m];
            #pragma unroll
            for (int i = 0; i < 4; ++i) {
                int r = q * 4 + i;
                A2[r * 136 + wv * 16 + m] = (short)f2bf(ssp_f(acc[i] + bv));
            }
        }
        __syncthreads();
        {
            f32x4 acc = {0.f, 0.f, 0.f, 0.f};
            #pragma unroll
            for (int ks = 0; ks < 2; ++ks) {
                short8_t a = *(const short8_t*)(A2 + m * 136 + ks * 32 + q * 8);
                short8_t b = *(const short8_t*)(o2p + (wv * 2 + ks) * 512 + lane * 8);
                acc = __builtin_amdgcn_mfma_f32_16x16x32_bf16(a, b, acc, 0, 0, 0);
            }
            float bv = o2b[wv * 16 + m];
            float part = acc[0] + acc[1] + acc[2] + acc[3] + 4.0f * bv;
            red[q][wv * 16 + m] = part;
        }
        __syncthreads();
        if (tid < 64) {
            float s = red[0][tid] + red[1][tid] + red[2][tid] + red[3][tid];
            atomicAdd(&gs[tid], s);
        }
    }
}

// out[i] = ro_b[i] + sum_k gs[k] * ro_w[k][i]
__global__ void final_kernel(const float* __restrict__ gs,
                             const float* __restrict__ ro_w,
                             const float* __restrict__ ro_b,
                             float* __restrict__ out) {
    int i = threadIdx.x;
    if (i < 12) {
        float s = ro_b[i];
        for (int k = 0; k < 64; ++k) s = fmaf(gs[k], ro_w[k * 12 + i], s);
        out[i] = s;
    }
}

// ---------------------------------------------------------------------------
extern "C" void kernel_launch(void* const* d_in, const int* in_sizes, int n_in,
                              void* d_out, int out_size, void* d_ws, size_t ws_size,
                              hipStream_t stream) {
    const int*   x      = (const int*)d_in[0];
    const int*   ei     = (const int*)d_in[1];
    const float* dist   = (const float*)d_in[2];
    const float* emb    = (const float*)d_in[3];
    const float* mlp_w1 = (const float*)d_in[4];
    const float* mlp_b1 = (const float*)d_in[5];
    const float* mlp_w2 = (const float*)d_in[6];
    const float* mlp_b2 = (const float*)d_in[7];
    const float* lin1_w = (const float*)d_in[8];
    const float* lin2_w = (const float*)d_in[9];
    const float* lin2_b = (const float*)d_in[10];
    const float* lin_w  = (const float*)d_in[11];
    const float* lin_b  = (const float*)d_in[12];
    const float* out1_w = (const float*)d_in[13];
    const float* out1_b = (const float*)d_in[14];
    const float* out2_w = (const float*)d_in[15];
    const float* out2_b = (const float*)d_in[16];
    const float* ro_w   = (const float*)d_in[17];
    const float* ro_b   = (const float*)d_in[18];
    float* out = (float*)d_out;

    // workspace layout
    char* base = (char*)d_ws;
    float*    h     = (float*)base;     base += (size_t)N_NUM * 128 * 4;
    ushort_t* tabB  = (ushort_t*)base;  base += (size_t)6 * TAB * 128 * 2;
    ushort_t* xf0   = (ushort_t*)base;  base += (size_t)N_NUM * 128 * 2;
    ushort_t* xf1   = (ushort_t*)base;  base += (size_t)N_NUM * 128 * 2;
    int*      meta  = (int*)base;       base += (size_t)E_NUM * 4;
    short*    wpack = (short*)base;     base += (size_t)WP_TOT * 2;
    float*    gs    = (float*)base;     base += 64 * 4;
    int*      offs  = (int*)base;       base += (N_NUM + 1) * 4;
    int*      cursor= (int*)base;       base += N_NUM * 4;
    int*      counts= (int*)base;       base += N_NUM * 4;
    int*      nperm = (int*)base;       base += N_NUM * 4;

    hipMemsetAsync(counts, 0, N_NUM * sizeof(int), stream);
    hipMemsetAsync(gs, 0, 64 * sizeof(float), stream);

    // sort edges by dst (once; dst constant across layers)
    hist_kernel<<<(E_NUM + 255) / 256, 256, 0, stream>>>(ei, counts);
    scan_kernel<<<1, 256, 0, stream>>>(counts, offs, cursor);
    scatter_kernel<<<(E_NUM + 255) / 256, 256, 0, stream>>>(ei, dist, cursor, meta);
    degsort_kernel<<<1, 256, 0, stream>>>(counts, nperm);

    // pack all weights (MFMA B-frag bf16), then build filter tables via MFMA
    pack_kernel<<<(WP_TOT + 255) / 256, 256, 0, stream>>>(
        lin2_w, lin_w, lin1_w, out1_w, out2_w, mlp_w1, mlp_w2, wpack);
    table_kernel<<<6 * (TAB / 16), 512, 0, stream>>>(
        wpack + WP_W1T, mlp_b1, wpack + WP_W2T, mlp_b2, tabB);

    // layer 0 front: h = emb[x], xf0 = bf16(h @ lin1_w[0])
    embed_lin1_kernel<<<NB8, 256, 0, stream>>>(x, emb, lin1_w, h, xf0);

    const short* o1p = wpack + WP_O1;
    const short* o2p = wpack + WP_O2;

    for (int l = 0; l < 6; ++l) {
        ushort_t* xin  = (l & 1) ? xf1 : xf0;
        ushort_t* xout = (l & 1) ? xf0 : xf1;
        const ushort_t* tl = tabB + (size_t)l * TAB * 128;
        const short* w2p = wpack + l * 16384;
        const short* wlp = wpack + (6 + l) * 16384;
        if (l < 5) {
            const short* w1p = wpack + (12 + l + 1) * 16384;   // lin1_w[l+1]
            layer_kernel<false><<<NB16, 256, 0, stream>>>(
                offs, nperm, meta, xin, tl,
                w2p, lin2_b + l * 128, wlp, lin_b + l * 128, w1p,
                h, xout, nullptr, nullptr, nullptr, nullptr, nullptr);
        } else {
            layer_kernel<true><<<NB16, 256, 0, stream>>>(
                offs, nperm, meta, xin, tl,
                w2p, lin2_b + l * 128, wlp, lin_b + l * 128, nullptr,
                h, nullptr, o1p, out1_b, o2p, out2_b, gs);
        }
    }

    final_kernel<<<1, 64, 0, stream>>>(gs, ro_w, ro_b, out);
}

// Round 13
// 336.203 us; speedup vs baseline: 1.0009x; 1.0009x over previous
//
#include <hip/hip_runtime.h>
#include <math.h>

#define E_NUM 320000
#define N_NUM 10000
#define NB8   (N_NUM / 8)           // 1250 blocks (embed)
#define NB16  (N_NUM / 16)          // 625 blocks (layer)
#define TAB   2048

typedef unsigned short ushort_t;
typedef short short8_t __attribute__((ext_vector_type(8)));   // 8 bf16 (4 VGPRs)
typedef float f32x4    __attribute__((ext_vector_type(4)));   // MFMA acc

// wpack layout (shorts):
//   [0)        6x lin2_w  128x128
//   [98304)    6x lin_w   128x128
//   [196608)   6x lin1_w  128x128
//   [294912)   o1w 128x64
//   [303104)   o2w 64x64
//   [307200)   6x mlp_w1  (K=64 zero-padded)x128  -> 8192 each
//   [356352)   6x mlp_w2  128x128                 -> 16384 each
#define WP_O1   294912
#define WP_O2   303104
#define WP_W1T  307200
#define WP_W2T  356352
#define WP_TOT  454656

__device__ __forceinline__ float ssp_f(float x) {
    return fmaxf(x, 0.f) + __logf(1.f + __expf(-fabsf(x))) - 0.69314718056f;
}

__device__ __forceinline__ float bf2f(ushort_t u) {
    union { unsigned int i; float f; } v;
    v.i = ((unsigned int)u) << 16;
    return v.f;
}
__device__ __forceinline__ ushort_t f2bf(float f) {
    union { float f; unsigned int i; } v;
    v.f = f;
    unsigned int u = v.i;
    unsigned int r = (u + 0x7FFFu + ((u >> 16) & 1u)) >> 16;   // RNE
    return (ushort_t)r;
}

// ---------------------------------------------------------------------------
// counting-sort phase 1: histogram of dst
__global__ __launch_bounds__(256) void hist_kernel(const int* __restrict__ ei,
                                                   int* __restrict__ counts) {
    int e = blockIdx.x * 256 + threadIdx.x;
    if (e < E_NUM) atomicAdd(&counts[ei[E_NUM + e]], 1);
}

// phase 2: exclusive scan over 10000 bins (single block)
__global__ __launch_bounds__(256) void scan_kernel(const int* __restrict__ counts,
                                                   int* __restrict__ offs,
                                                   int* __restrict__ cursor) {
    __shared__ int part[256];
    const int tid = threadIdx.x;
    const int CH = 40;
    int base = tid * CH;
    int s = 0;
    for (int i = 0; i < CH; ++i) {
        int idx = base + i;
        if (idx < N_NUM) s += counts[idx];
    }
    part[tid] = s;
    __syncthreads();
    for (int off = 1; off < 256; off <<= 1) {
        int v = (tid >= off) ? part[tid - off] : 0;
        __syncthreads();
        part[tid] += v;
        __syncthreads();
    }
    int run = (tid > 0) ? part[tid - 1] : 0;
    for (int i = 0; i < CH; ++i) {
        int idx = base + i;
        if (idx < N_NUM) {
            offs[idx] = run;
            cursor[idx] = run;
            run += counts[idx];
        }
    }
    if (tid == 255) offs[N_NUM] = part[255];
}

// phase 3: scatter edges to dst-sorted order.
// meta = (i0 << 14) | src ; i0 = nearest table row (11 bits), src 14 bits.
__global__ __launch_bounds__(256) void scatter_kernel(const int* __restrict__ ei,
                                                      const float* __restrict__ dist,
                                                      int* __restrict__ cursor,
                                                      int* __restrict__ meta) {
    int e = blockIdx.x * 256 + threadIdx.x;
    if (e >= E_NUM) return;
    int d = ei[E_NUM + e];
    int pos = atomicAdd(&cursor[d], 1);
    float t = dist[e] * ((float)(TAB - 1) / 10.0f);
    int i0 = (int)(t + 0.5f);
    if (i0 > TAB - 1) i0 = TAB - 1;
    meta[pos] = (i0 << 14) | ei[e];
}

// ---------------------------------------------------------------------------
// Pack all weights into MFMA B-fragment order (bf16).
// B-frag: idx = ((t*KSP + ks)*64 + L)*8 + j ; n = t*16+(L&15), k = ks*32+(L>>4)*8+j
__global__ __launch_bounds__(256) void pack_kernel(const float* __restrict__ lin2_w,
                                                   const float* __restrict__ lin_w,
                                                   const float* __restrict__ lin1_w,
                                                   const float* __restrict__ o1w,
                                                   const float* __restrict__ o2w,
                                                   const float* __restrict__ mlp_w1,
                                                   const float* __restrict__ mlp_w2,
                                                   short* __restrict__ wpack) {
    int idx = blockIdx.x * 256 + threadIdx.x;
    const int M128 = 16384;
    if (idx < 18 * M128) {
        int g = idx / M128, r = idx % M128;
        const float* src;
        if (g < 6) src = lin2_w + g * M128;
        else if (g < 12) src = lin_w + (g - 6) * M128;
        else src = lin1_w + (g - 12) * M128;
        int j = r & 7, L = (r >> 3) & 63, ks = (r >> 9) & 3, t = r >> 11;
        int n = t * 16 + (L & 15);
        int k = ks * 32 + (L >> 4) * 8 + j;
        wpack[idx] = (short)f2bf(src[k * 128 + n]);
    } else if (idx < WP_O2) {
        int r = idx - WP_O1;              // o1w: K=128, N=64
        int j = r & 7, L = (r >> 3) & 63, ks = (r >> 9) & 3, t = r >> 11;
        int n = t * 16 + (L & 15);
        int k = ks * 32 + (L >> 4) * 8 + j;
        wpack[idx] = (short)f2bf(o1w[k * 64 + n]);
    } else if (idx < WP_W1T) {
        int r = idx - WP_O2;              // o2w: K=64, N=64
        int j = r & 7, L = (r >> 3) & 63, ks = (r >> 9) & 1, t = r >> 10;
        int n = t * 16 + (L & 15);
        int k = ks * 32 + (L >> 4) * 8 + j;
        wpack[idx] = (short)f2bf(o2w[k * 64 + n]);
    } else if (idx < WP_W2T) {
        int r2 = idx - WP_W1T;            // mlp_w1: K=50 pad to 64, N=128
        int g = r2 / 8192, r = r2 % 8192;
        int j = r & 7, L = (r >> 3) & 63, ks = (r >> 9) & 1, t = r >> 10;
        int n = t * 16 + (L & 15);
        int k = ks * 32 + (L >> 4) * 8 + j;
        float v = (k < 50) ? mlp_w1[g * 6400 + k * 128 + n] : 0.f;
        wpack[idx] = (short)f2bf(v);
    } else if (idx < WP_TOT) {
        int r2 = idx - WP_W2T;            // mlp_w2: K=128, N=128
        int g = r2 / M128, r = r2 % M128;
        int j = r & 7, L = (r >> 3) & 63, ks = (r >> 9) & 3, t = r >> 11;
        int n = t * 16 + (L & 15);
        int k = ks * 32 + (L >> 4) * 8 + j;
        wpack[idx] = (short)f2bf(mlp_w2[g * M128 + k * 128 + n]);
    }
}

// ---------------------------------------------------------------------------
// MFMA table build: plain row layout tab[l][i][c] (bf16), nearest-neighbor use.
// 16 d-rows/block, 512 threads, 6*(TAB/16) = 768 blocks.
__global__ __launch_bounds__(512) void table_kernel(const short* __restrict__ w1t,
                                                    const float* __restrict__ mlp_b1,
                                                    const short* __restrict__ w2t,
                                                    const float* __restrict__ mlp_b2,
                                                    ushort_t* __restrict__ tabB) {
    __shared__ short EA[16 * 72];    // bf16 gaussians, K padded to 64
    __shared__ short HD[16 * 136];   // bf16 hidden
    const int tid = threadIdx.x;
    const int wv = tid >> 6;
    const int lane = tid & 63;
    const int l = blockIdx.x >> 7;              // / (TAB/16 = 128)
    const int r0 = (blockIdx.x & 127) * 16;
    const float DG = 10.0f / (float)(TAB - 1);
    const float STEP = 10.0f / 49.0f;
    const float COEFF = -0.5f / (STEP * STEP);

    for (int i = tid; i < 16 * 64; i += 512) {
        int r = i >> 6, k = i & 63;
        float v = 0.f;
        if (k < 50) {
            float d = (float)(r0 + r) * DG;
            float t = d - (float)k * STEP;
            v = __expf(COEFF * t * t);
        }
        EA[r * 72 + k] = (short)f2bf(v);
    }
    __syncthreads();

    const int m = lane & 15, q = lane >> 4;

    // stage 1: hidden = ssp(ea @ w1 + b1), K=64 (padded)
    {
        f32x4 acc = {0.f, 0.f, 0.f, 0.f};
        #pragma unroll
        for (int ks = 0; ks < 2; ++ks) {
            short8_t a = *(const short8_t*)(EA + m * 72 + ks * 32 + q * 8);
            short8_t b = *(const short8_t*)(w1t + l * 8192 + (wv * 2 + ks) * 512 + lane * 8);
            acc = __builtin_amdgcn_mfma_f32_16x16x32_bf16(a, b, acc, 0, 0, 0);
        }
        float bv = mlp_b1[l * 128 + wv * 16 + m];
        #pragma unroll
        for (int i = 0; i < 4; ++i)
            HD[(q * 4 + i) * 136 + wv * 16 + m] = (short)f2bf(ssp_f(acc[i] + bv));
    }
    __syncthreads();

    // stage 2: W = hidden @ w2 + b2, *C(d), plain row write
    {
        f32x4 acc = {0.f, 0.f, 0.f, 0.f};
        #pragma unroll
        for (int ks = 0; ks < 4; ++ks) {
            short8_t a = *(const short8_t*)(HD + m * 136 + ks * 32 + q * 8);
            short8_t b = *(const short8_t*)(w2t + l * 16384 + (wv * 4 + ks) * 512 + lane * 8);
            acc = __builtin_amdgcn_mfma_f32_16x16x32_bf16(a, b, acc, 0, 0, 0);
        }
        int col = wv * 16 + m;
        float bv = mlp_b2[l * 128 + col];
        ushort_t* tl = tabB + (size_t)l * TAB * 128;
        #pragma unroll
        for (int i = 0; i < 4; ++i) {
            int row = r0 + q * 4 + i;
            float d = (float)row * DG;
            float C = 0.5f * (__cosf(d * 0.31415926535f) + 1.0f);
            tl[(size_t)row * 128 + col] = f2bf((acc[i] + bv) * C);
        }
    }
}

// ---------------------------------------------------------------------------
// nearest-neighbor accumulate: 8 cols/lane, one edge
__device__ __forceinline__ void nacc8(short8_t x, short8_t t, float* o) {
    #pragma unroll
    for (int j = 0; j < 8; ++j)
        o[j] = fmaf(bf2f((ushort_t)x[j]), bf2f((ushort_t)t[j]), o[j]);
}

// ---------------------------------------------------------------------------
// Layer 0 front: h = emb[x]; xf = bf16(h @ lin1_w[0]).  8 rows/block, 256 thr.
__global__ __launch_bounds__(256) void embed_lin1_kernel(const int* __restrict__ x,
                                                         const float* __restrict__ emb,
                                                         const float* __restrict__ B,
                                                         float* __restrict__ h,
                                                         ushort_t* __restrict__ xf) {
    __shared__ float AT[128][9];
    __shared__ int s_x[8];
    const int tid = threadIdx.x;
    const int n0 = blockIdx.x * 8;

    if (tid < 8) s_x[tid] = x[n0 + tid];
    __syncthreads();
    for (int i = tid; i < 8 * 128; i += 256) {
        int r = i >> 7, c = i & 127;
        float v = emb[s_x[r] * 128 + c];
        AT[c][r] = v;
        h[(size_t)(n0 + r) * 128 + c] = v;
    }
    __syncthreads();

    const int r  = tid & 7;
    const int c0 = (tid >> 3) * 4;
    float acc[4] = {0.f, 0.f, 0.f, 0.f};
    for (int k = 0; k < 128; k += 4) {
        float a[4];
        #pragma unroll
        for (int u = 0; u < 4; ++u) a[u] = AT[k + u][r];
        #pragma unroll
        for (int u = 0; u < 4; ++u) {
            float4 b = *(const float4*)(B + (size_t)(k + u) * 128 + c0);
            acc[0] = fmaf(a[u], b.x, acc[0]);
            acc[1] = fmaf(a[u], b.y, acc[1]);
            acc[2] = fmaf(a[u], b.z, acc[2]);
            acc[3] = fmaf(a[u], b.w, acc[3]);
        }
    }
    ushort4 o;
    o.x = f2bf(acc[0]); o.y = f2bf(acc[1]); o.z = f2bf(acc[2]); o.w = f2bf(acc[3]);
    *(ushort4*)(xf + (size_t)(n0 + r) * 128 + c0) = o;
}

// ---------------------------------------------------------------------------
// Fused MFMA layer kernel: 16 nodes/block, 512 threads (8 waves).
// phase A: 32 quarter-wave edge streams — each node's edge list is SPLIT IN
//   HALF across two quarter-streams (16 lanes x 8 cols, 16B/lane loads; one
//   wave instr serves 4 edges). Halves combine in fp32 LDS before bf16 round.
// MFMA stages: wave wv computes col-tile wv.
template <bool LAST>
__global__ __launch_bounds__(512) void layer_kernel(const int* __restrict__ offs,
                                                    const int* __restrict__ meta,
                                                    const ushort_t* __restrict__ xf,
                                                    const ushort_t* __restrict__ tabB,
                                                    const short* __restrict__ w2p,
                                                    const float* __restrict__ lin2_b,
                                                    const short* __restrict__ wlp,
                                                    const float* __restrict__ lin_b,
                                                    const short* __restrict__ w1p,
                                                    float* __restrict__ h,
                                                    ushort_t* __restrict__ xf_out,
                                                    const short* __restrict__ o1p,
                                                    const float* __restrict__ o1b,
                                                    const short* __restrict__ o2p,
                                                    const float* __restrict__ o2b,
                                                    float* __restrict__ gs) {
    __shared__ short A1[16 * 136];   // bf16, row stride 136 shorts (272 B)
    __shared__ short A2[16 * 136];
    __shared__ float PF[32][132];    // fp32 partial sums (2 halves per node)
    __shared__ float red[4][64];
    const int tid = threadIdx.x;
    const int n0 = blockIdx.x * 16;
    const int wv = tid >> 6;         // 0..7
    const int lane = tid & 63;

    // ---- phase A: 32 split edge streams, nearest table row ----
    {
        const int qt = lane >> 4;        // 0..3
        const int c8 = (lane & 15) * 8;  // 8 cols/lane
        const int s = wv * 4 + qt;       // stream 0..31
        const int node = n0 + (s >> 1);
        const int half = s & 1;
        int beg = offs[node], end = offs[node + 1];
        int mid = beg + ((end - beg) >> 1);
        int e    = half ? mid : beg;
        int stop = half ? end : mid;

        float accA[8] = {0.f, 0.f, 0.f, 0.f, 0.f, 0.f, 0.f, 0.f};
        float accB[8] = {0.f, 0.f, 0.f, 0.f, 0.f, 0.f, 0.f, 0.f};

        for (; e + 8 <= stop; e += 8) {
            int m[8];
            #pragma unroll
            for (int u = 0; u < 8; ++u) m[u] = meta[e + u];
            short8_t xv[8], tv[8];
            #pragma unroll
            for (int u = 0; u < 8; ++u) {
                xv[u] = *(const short8_t*)(xf + (size_t)(m[u] & 0x3FFF) * 128 + c8);
                tv[u] = *(const short8_t*)(tabB + (size_t)((unsigned)m[u] >> 14) * 128 + c8);
            }
            #pragma unroll
            for (int u = 0; u < 8; ++u)
                nacc8(xv[u], tv[u], (u & 1) ? accB : accA);
        }
        for (; e + 4 <= stop; e += 4) {
            int m[4];
            #pragma unroll
            for (int u = 0; u < 4; ++u) m[u] = meta[e + u];
            short8_t xv[4], tv[4];
            #pragma unroll
            for (int u = 0; u < 4; ++u) {
                xv[u] = *(const short8_t*)(xf + (size_t)(m[u] & 0x3FFF) * 128 + c8);
                tv[u] = *(const short8_t*)(tabB + (size_t)((unsigned)m[u] >> 14) * 128 + c8);
            }
            #pragma unroll
            for (int u = 0; u < 4; ++u)
                nacc8(xv[u], tv[u], (u & 1) ? accB : accA);
        }
        for (; e < stop; ++e) {
            int mm = meta[e];
            short8_t xv = *(const short8_t*)(xf + (size_t)(mm & 0x3FFF) * 128 + c8);
            short8_t tv = *(const short8_t*)(tabB + (size_t)((unsigned)mm >> 14) * 128 + c8);
            nacc8(xv, tv, accA);
        }

        float4 p0, p1;
        p0.x = accA[0] + accB[0]; p0.y = accA[1] + accB[1];
        p0.z = accA[2] + accB[2]; p0.w = accA[3] + accB[3];
        p1.x = accA[4] + accB[4]; p1.y = accA[5] + accB[5];
        p1.z = accA[6] + accB[6]; p1.w = accA[7] + accB[7];
        *(float4*)&PF[s][c8]     = p0;
        *(float4*)&PF[s][c8 + 4] = p1;
    }
    __syncthreads();

    // combine halves -> bf16 A1
    for (int idx = tid; idx < 16 * 128; idx += 512) {
        int r = idx >> 7, c = idx & 127;
        A1[r * 136 + c] = (short)f2bf(PF[2 * r][c] + PF[2 * r + 1][c]);
    }
    __syncthreads();

    const int m = lane & 15, q = lane >> 4;

    // ---- stage 1: t = ssp(agg @ lin2_w + lin2_b) -> A2 ----
    {
        f32x4 acc = {0.f, 0.f, 0.f, 0.f};
        #pragma unroll
        for (int ks = 0; ks < 4; ++ks) {
            short8_t a = *(const short8_t*)(A1 + m * 136 + ks * 32 + q * 8);
            short8_t b = *(const short8_t*)(w2p + (wv * 4 + ks) * 512 + lane * 8);
            acc = __builtin_amdgcn_mfma_f32_16x16x32_bf16(a, b, acc, 0, 0, 0);
        }
        float bv = lin2_b[wv * 16 + m];
        #pragma unroll
        for (int i = 0; i < 4; ++i) {
            int r = q * 4 + i;
            A2[r * 136 + wv * 16 + m] = (short)f2bf(ssp_f(acc[i] + bv));
        }
    }
    __syncthreads();

    // ---- stage 2: h_new = h + t @ lin_w + lin_b -> A1 (+ global h if !LAST) ----
    {
        f32x4 acc = {0.f, 0.f, 0.f, 0.f};
        #pragma unroll
        for (int ks = 0; ks < 4; ++ks) {
            short8_t a = *(const short8_t*)(A2 + m * 136 + ks * 32 + q * 8);
            short8_t b = *(const short8_t*)(wlp + (wv * 4 + ks) * 512 + lane * 8);
            acc = __builtin_amdgcn_mfma_f32_16x16x32_bf16(a, b, acc, 0, 0, 0);
        }
        float bv = lin_b[wv * 16 + m];
        #pragma unroll
        for (int i = 0; i < 4; ++i) {
            int r = q * 4 + i;
            int grow = n0 + r;
            float h0 = h[(size_t)grow * 128 + wv * 16 + m];
            float hn = h0 + acc[i] + bv;
            if (!LAST) h[(size_t)grow * 128 + wv * 16 + m] = hn;
            A1[r * 136 + wv * 16 + m] = (short)f2bf(hn);
        }
    }
    __syncthreads();

    if constexpr (!LAST) {
        // ---- stage 3: xf_out = bf16(h_new @ lin1_next) ----
        f32x4 acc = {0.f, 0.f, 0.f, 0.f};
        #pragma unroll
        for (int ks = 0; ks < 4; ++ks) {
            short8_t a = *(const short8_t*)(A1 + m * 136 + ks * 32 + q * 8);
            short8_t b = *(const short8_t*)(w1p + (wv * 4 + ks) * 512 + lane * 8);
            acc = __builtin_amdgcn_mfma_f32_16x16x32_bf16(a, b, acc, 0, 0, 0);
        }
        #pragma unroll
        for (int i = 0; i < 4; ++i) {
            int r = q * 4 + i;
            int grow = n0 + r;
            xf_out[(size_t)grow * 128 + wv * 16 + m] = f2bf(acc[i]);
        }
    } else {
        // ---- fused head: waves 0-3 compute o1/o2 col-tiles; colsum -> gs ----
        if (wv < 4) {
            f32x4 acc = {0.f, 0.f, 0.f, 0.f};
            #pragma unroll
            for (int ks = 0; ks < 4; ++ks) {
                short8_t a = *(const short8_t*)(A1 + m * 136 + ks * 32 + q * 8);
                short8_t b = *(const short8_t*)(o1p + (wv * 4 + ks) * 512 + lane * 8);
                acc = __builtin_amdgcn_mfma_f32_16x16x32_bf16(a, b, acc, 0, 0, 0);
            }
            float bv = o1b[wv * 16 + m];
            #pragma unroll
            for (int i = 0; i < 4; ++i) {
                int r = q * 4 + i;
                A2[r * 136 + wv * 16 + m] = (short)f2bf(ssp_f(acc[i] + bv));
            }
        }
        __syncthreads();
        if (wv < 4) {
            f32x4 acc = {0.f, 0.f, 0.f, 0.f};
            #pragma unroll
            for (int ks = 0; ks < 2; ++ks) {
                short8_t a = *(const short8_t*)(A2 + m * 136 + ks * 32 + q * 8);
                short8_t b = *(const short8_t*)(o2p + (wv * 2 + ks) * 512 + lane * 8);
                acc = __builtin_amdgcn_mfma_f32_16x16x32_bf16(a, b, acc, 0, 0, 0);
            }
            float bv = o2b[wv * 16 + m];
            float part = acc[0] + acc[1] + acc[2] + acc[3] + 4.0f * bv;
            red[q][wv * 16 + m] = part;
        }
        __syncthreads();
        if (tid < 64) {
            float s = red[0][tid] + red[1][tid] + red[2][tid] + red[3][tid];
            atomicAdd(&gs[tid], s);
        }
    }
}

// out[i] = ro_b[i] + sum_k gs[k] * ro_w[k][i]
__global__ void final_kernel(const float* __restrict__ gs,
                             const float* __restrict__ ro_w,
                             const float* __restrict__ ro_b,
                             float* __restrict__ out) {
    int i = threadIdx.x;
    if (i < 12) {
        float s = ro_b[i];
        for (int k = 0; k < 64; ++k) s = fmaf(gs[k], ro_w[k * 12 + i], s);
        out[i] = s;
    }
}

// ---------------------------------------------------------------------------
extern "C" void kernel_launch(void* const* d_in, const int* in_sizes, int n_in,
                              void* d_out, int out_size, void* d_ws, size_t ws_size,
                              hipStream_t stream) {
    const int*   x      = (const int*)d_in[0];
    const int*   ei     = (const int*)d_in[1];
    const float* dist   = (const float*)d_in[2];
    const float* emb    = (const float*)d_in[3];
    const float* mlp_w1 = (const float*)d_in[4];
    const float* mlp_b1 = (const float*)d_in[5];
    const float* mlp_w2 = (const float*)d_in[6];
    const float* mlp_b2 = (const float*)d_in[7];
    const float* lin1_w = (const float*)d_in[8];
    const float* lin2_w = (const float*)d_in[9];
    const float* lin2_b = (const float*)d_in[10];
    const float* lin_w  = (const float*)d_in[11];
    const float* lin_b  = (const float*)d_in[12];
    const float* out1_w = (const float*)d_in[13];
    const float* out1_b = (const float*)d_in[14];
    const float* out2_w = (const float*)d_in[15];
    const float* out2_b = (const float*)d_in[16];
    const float* ro_w   = (const float*)d_in[17];
    const float* ro_b   = (const float*)d_in[18];
    float* out = (float*)d_out;

    // workspace layout
    char* base = (char*)d_ws;
    float*    h     = (float*)base;     base += (size_t)N_NUM * 128 * 4;
    ushort_t* tabB  = (ushort_t*)base;  base += (size_t)6 * TAB * 128 * 2;
    ushort_t* xf0   = (ushort_t*)base;  base += (size_t)N_NUM * 128 * 2;
    ushort_t* xf1   = (ushort_t*)base;  base += (size_t)N_NUM * 128 * 2;
    int*      meta  = (int*)base;       base += (size_t)E_NUM * 4;
    short*    wpack = (short*)base;     base += (size_t)WP_TOT * 2;
    float*    gs    = (float*)base;     base += 64 * 4;
    int*      offs  = (int*)base;       base += (N_NUM + 1) * 4;
    int*      cursor= (int*)base;       base += N_NUM * 4;
    int*      counts= (int*)base;       base += N_NUM * 4;

    hipMemsetAsync(counts, 0, N_NUM * sizeof(int), stream);
    hipMemsetAsync(gs, 0, 64 * sizeof(float), stream);

    // sort edges by dst (once; dst constant across layers)
    hist_kernel<<<(E_NUM + 255) / 256, 256, 0, stream>>>(ei, counts);
    scan_kernel<<<1, 256, 0, stream>>>(counts, offs, cursor);
    scatter_kernel<<<(E_NUM + 255) / 256, 256, 0, stream>>>(ei, dist, cursor, meta);

    // pack all weights (MFMA B-frag bf16), then build filter tables via MFMA
    pack_kernel<<<(WP_TOT + 255) / 256, 256, 0, stream>>>(
        lin2_w, lin_w, lin1_w, out1_w, out2_w, mlp_w1, mlp_w2, wpack);
    table_kernel<<<6 * (TAB / 16), 512, 0, stream>>>(
        wpack + WP_W1T, mlp_b1, wpack + WP_W2T, mlp_b2, tabB);

    // layer 0 front: h = emb[x], xf0 = bf16(h @ lin1_w[0])
    embed_lin1_kernel<<<NB8, 256, 0, stream>>>(x, emb, lin1_w, h, xf0);

    const short* o1p = wpack + WP_O1;
    const short* o2p = wpack + WP_O2;

    for (int l = 0; l < 6; ++l) {
        ushort_t* xin  = (l & 1) ? xf1 : xf0;
        ushort_t* xout = (l & 1) ? xf0 : xf1;
        const ushort_t* tl = tabB + (size_t)l * TAB * 128;
        const short* w2p = wpack + l * 16384;
        const short* wlp = wpack + (6 + l) * 16384;
        if (l < 5) {
            const short* w1p = wpack + (12 + l + 1) * 16384;   // lin1_w[l+1]
            layer_kernel<false><<<NB16, 512, 0, stream>>>(
                offs, meta, xin, tl,
                w2p, lin2_b + l * 128, wlp, lin_b + l * 128, w1p,
                h, xout, nullptr, nullptr, nullptr, nullptr, nullptr);
        } else {
            layer_kernel<true><<<NB16, 512, 0, stream>>>(
                offs, meta, xin, tl,
                w2p, lin2_b + l * 128, wlp, lin_b + l * 128, nullptr,
                h, nullptr, o1p, out1_b, o2p, out2_b, gs);
        }
    }

    final_kernel<<<1, 64, 0, stream>>>(gs, ro_w, ro_b, out);
}

// Round 14
// 320.054 us; speedup vs baseline: 1.0514x; 1.0505x over previous
//
#include <hip/hip_runtime.h>
#include <math.h>

#define E_NUM 320000
#define N_NUM 10000
#define NB8   (N_NUM / 8)           // 1250 blocks (embed)
#define NB16  (N_NUM / 16)          // 625 blocks (layer)
#define TAB   2048

typedef unsigned short ushort_t;
typedef short short8_t __attribute__((ext_vector_type(8)));   // 8 bf16 (4 VGPRs)
typedef float f32x4    __attribute__((ext_vector_type(4)));   // MFMA acc

// wpack layout (shorts):
//   [0)        6x lin2_w  128x128
//   [98304)    6x lin_w   128x128
//   [196608)   6x lin1_w  128x128
//   [294912)   o1w 128x64
//   [303104)   o2w 64x64
//   [307200)   6x mlp_w1  (K=64 zero-padded)x128  -> 8192 each
//   [356352)   6x mlp_w2  128x128                 -> 16384 each
#define WP_O1   294912
#define WP_O2   303104
#define WP_W1T  307200
#define WP_W2T  356352
#define WP_TOT  454656

__device__ __forceinline__ float ssp_f(float x) {
    return fmaxf(x, 0.f) + __logf(1.f + __expf(-fabsf(x))) - 0.69314718056f;
}

__device__ __forceinline__ float bf2f(ushort_t u) {
    union { unsigned int i; float f; } v;
    v.i = ((unsigned int)u) << 16;
    return v.f;
}
__device__ __forceinline__ ushort_t f2bf(float f) {
    union { float f; unsigned int i; } v;
    v.f = f;
    unsigned int u = v.i;
    unsigned int r = (u + 0x7FFFu + ((u >> 16) & 1u)) >> 16;   // RNE
    return (ushort_t)r;
}

// ---------------------------------------------------------------------------
// counting-sort phase 1: histogram of dst
__global__ __launch_bounds__(256) void hist_kernel(const int* __restrict__ ei,
                                                   int* __restrict__ counts) {
    int e = blockIdx.x * 256 + threadIdx.x;
    if (e < E_NUM) atomicAdd(&counts[ei[E_NUM + e]], 1);
}

// phase 2: exclusive scan over 10000 bins (single block)
__global__ __launch_bounds__(256) void scan_kernel(const int* __restrict__ counts,
                                                   int* __restrict__ offs,
                                                   int* __restrict__ cursor) {
    __shared__ int part[256];
    const int tid = threadIdx.x;
    const int CH = 40;
    int base = tid * CH;
    int s = 0;
    for (int i = 0; i < CH; ++i) {
        int idx = base + i;
        if (idx < N_NUM) s += counts[idx];
    }
    part[tid] = s;
    __syncthreads();
    for (int off = 1; off < 256; off <<= 1) {
        int v = (tid >= off) ? part[tid - off] : 0;
        __syncthreads();
        part[tid] += v;
        __syncthreads();
    }
    int run = (tid > 0) ? part[tid - 1] : 0;
    for (int i = 0; i < CH; ++i) {
        int idx = base + i;
        if (idx < N_NUM) {
            offs[idx] = run;
            cursor[idx] = run;
            run += counts[idx];
        }
    }
    if (tid == 255) offs[N_NUM] = part[255];
}

// phase 3: scatter edges to dst-sorted order.
// meta = (i0 << 14) | src ; i0 = nearest table row (11 bits), src 14 bits.
__global__ __launch_bounds__(256) void scatter_kernel(const int* __restrict__ ei,
                                                      const float* __restrict__ dist,
                                                      int* __restrict__ cursor,
                                                      int* __restrict__ meta) {
    int e = blockIdx.x * 256 + threadIdx.x;
    if (e >= E_NUM) return;
    int d = ei[E_NUM + e];
    int pos = atomicAdd(&cursor[d], 1);
    float t = dist[e] * ((float)(TAB - 1) / 10.0f);
    int i0 = (int)(t + 0.5f);
    if (i0 > TAB - 1) i0 = TAB - 1;
    meta[pos] = (i0 << 14) | ei[e];
}

// ---------------------------------------------------------------------------
// Pack all weights into MFMA B-fragment order (bf16).
// B-frag: idx = ((t*KSP + ks)*64 + L)*8 + j ; n = t*16+(L&15), k = ks*32+(L>>4)*8+j
__global__ __launch_bounds__(256) void pack_kernel(const float* __restrict__ lin2_w,
                                                   const float* __restrict__ lin_w,
                                                   const float* __restrict__ lin1_w,
                                                   const float* __restrict__ o1w,
                                                   const float* __restrict__ o2w,
                                                   const float* __restrict__ mlp_w1,
                                                   const float* __restrict__ mlp_w2,
                                                   short* __restrict__ wpack) {
    int idx = blockIdx.x * 256 + threadIdx.x;
    const int M128 = 16384;
    if (idx < 18 * M128) {
        int g = idx / M128, r = idx % M128;
        const float* src;
        if (g < 6) src = lin2_w + g * M128;
        else if (g < 12) src = lin_w + (g - 6) * M128;
        else src = lin1_w + (g - 12) * M128;
        int j = r & 7, L = (r >> 3) & 63, ks = (r >> 9) & 3, t = r >> 11;
        int n = t * 16 + (L & 15);
        int k = ks * 32 + (L >> 4) * 8 + j;
        wpack[idx] = (short)f2bf(src[k * 128 + n]);
    } else if (idx < WP_O2) {
        int r = idx - WP_O1;              // o1w: K=128, N=64
        int j = r & 7, L = (r >> 3) & 63, ks = (r >> 9) & 3, t = r >> 11;
        int n = t * 16 + (L & 15);
        int k = ks * 32 + (L >> 4) * 8 + j;
        wpack[idx] = (short)f2bf(o1w[k * 64 + n]);
    } else if (idx < WP_W1T) {
        int r = idx - WP_O2;              // o2w: K=64, N=64
        int j = r & 7, L = (r >> 3) & 63, ks = (r >> 9) & 1, t = r >> 10;
        int n = t * 16 + (L & 15);
        int k = ks * 32 + (L >> 4) * 8 + j;
        wpack[idx] = (short)f2bf(o2w[k * 64 + n]);
    } else if (idx < WP_W2T) {
        int r2 = idx - WP_W1T;            // mlp_w1: K=50 pad to 64, N=128
        int g = r2 / 8192, r = r2 % 8192;
        int j = r & 7, L = (r >> 3) & 63, ks = (r >> 9) & 1, t = r >> 10;
        int n = t * 16 + (L & 15);
        int k = ks * 32 + (L >> 4) * 8 + j;
        float v = (k < 50) ? mlp_w1[g * 6400 + k * 128 + n] : 0.f;
        wpack[idx] = (short)f2bf(v);
    } else if (idx < WP_TOT) {
        int r2 = idx - WP_W2T;            // mlp_w2: K=128, N=128
        int g = r2 / M128, r = r2 % M128;
        int j = r & 7, L = (r >> 3) & 63, ks = (r >> 9) & 3, t = r >> 11;
        int n = t * 16 + (L & 15);
        int k = ks * 32 + (L >> 4) * 8 + j;
        wpack[idx] = (short)f2bf(mlp_w2[g * M128 + k * 128 + n]);
    }
}

// ---------------------------------------------------------------------------
// MFMA table build: plain row layout tab[l][i][c] (bf16), nearest-neighbor use.
// 16 d-rows/block, 512 threads, 6*(TAB/16) = 768 blocks.
__global__ __launch_bounds__(512) void table_kernel(const short* __restrict__ w1t,
                                                    const float* __restrict__ mlp_b1,
                                                    const short* __restrict__ w2t,
                                                    const float* __restrict__ mlp_b2,
                                                    ushort_t* __restrict__ tabB) {
    __shared__ short EA[16 * 72];    // bf16 gaussians, K padded to 64
    __shared__ short HD[16 * 136];   // bf16 hidden
    const int tid = threadIdx.x;
    const int wv = tid >> 6;
    const int lane = tid & 63;
    const int l = blockIdx.x >> 7;              // / (TAB/16 = 128)
    const int r0 = (blockIdx.x & 127) * 16;
    const float DG = 10.0f / (float)(TAB - 1);
    const float STEP = 10.0f / 49.0f;
    const float COEFF = -0.5f / (STEP * STEP);

    for (int i = tid; i < 16 * 64; i += 512) {
        int r = i >> 6, k = i & 63;
        float v = 0.f;
        if (k < 50) {
            float d = (float)(r0 + r) * DG;
            float t = d - (float)k * STEP;
            v = __expf(COEFF * t * t);
        }
        EA[r * 72 + k] = (short)f2bf(v);
    }
    __syncthreads();

    const int m = lane & 15, q = lane >> 4;

    // stage 1: hidden = ssp(ea @ w1 + b1), K=64 (padded)
    {
        f32x4 acc = {0.f, 0.f, 0.f, 0.f};
        #pragma unroll
        for (int ks = 0; ks < 2; ++ks) {
            short8_t a = *(const short8_t*)(EA + m * 72 + ks * 32 + q * 8);
            short8_t b = *(const short8_t*)(w1t + l * 8192 + (wv * 2 + ks) * 512 + lane * 8);
            acc = __builtin_amdgcn_mfma_f32_16x16x32_bf16(a, b, acc, 0, 0, 0);
        }
        float bv = mlp_b1[l * 128 + wv * 16 + m];
        #pragma unroll
        for (int i = 0; i < 4; ++i)
            HD[(q * 4 + i) * 136 + wv * 16 + m] = (short)f2bf(ssp_f(acc[i] + bv));
    }
    __syncthreads();

    // stage 2: W = hidden @ w2 + b2, *C(d), plain row write
    {
        f32x4 acc = {0.f, 0.f, 0.f, 0.f};
        #pragma unroll
        for (int ks = 0; ks < 4; ++ks) {
            short8_t a = *(const short8_t*)(HD + m * 136 + ks * 32 + q * 8);
            short8_t b = *(const short8_t*)(w2t + l * 16384 + (wv * 4 + ks) * 512 + lane * 8);
            acc = __builtin_amdgcn_mfma_f32_16x16x32_bf16(a, b, acc, 0, 0, 0);
        }
        int col = wv * 16 + m;
        float bv = mlp_b2[l * 128 + col];
        ushort_t* tl = tabB + (size_t)l * TAB * 128;
        #pragma unroll
        for (int i = 0; i < 4; ++i) {
            int row = r0 + q * 4 + i;
            float d = (float)row * DG;
            float C = 0.5f * (__cosf(d * 0.31415926535f) + 1.0f);
            tl[(size_t)row * 128 + col] = f2bf((acc[i] + bv) * C);
        }
    }
}

// ---------------------------------------------------------------------------
// nearest-neighbor accumulate: 8 cols/lane, one edge
__device__ __forceinline__ void nacc8(short8_t x, short8_t t, float* o) {
    #pragma unroll
    for (int j = 0; j < 8; ++j)
        o[j] = fmaf(bf2f((ushort_t)x[j]), bf2f((ushort_t)t[j]), o[j]);
}

// ---------------------------------------------------------------------------
// Layer 0 front: h = emb[x]; xf = bf16(h @ lin1_w[0]).  8 rows/block, 256 thr.
__global__ __launch_bounds__(256) void embed_lin1_kernel(const int* __restrict__ x,
                                                         const float* __restrict__ emb,
                                                         const float* __restrict__ B,
                                                         float* __restrict__ h,
                                                         ushort_t* __restrict__ xf) {
    __shared__ float AT[128][9];
    __shared__ int s_x[8];
    const int tid = threadIdx.x;
    const int n0 = blockIdx.x * 8;

    if (tid < 8) s_x[tid] = x[n0 + tid];
    __syncthreads();
    for (int i = tid; i < 8 * 128; i += 256) {
        int r = i >> 7, c = i & 127;
        float v = emb[s_x[r] * 128 + c];
        AT[c][r] = v;
        h[(size_t)(n0 + r) * 128 + c] = v;
    }
    __syncthreads();

    const int r  = tid & 7;
    const int c0 = (tid >> 3) * 4;
    float acc[4] = {0.f, 0.f, 0.f, 0.f};
    for (int k = 0; k < 128; k += 4) {
        float a[4];
        #pragma unroll
        for (int u = 0; u < 4; ++u) a[u] = AT[k + u][r];
        #pragma unroll
        for (int u = 0; u < 4; ++u) {
            float4 b = *(const float4*)(B + (size_t)(k + u) * 128 + c0);
            acc[0] = fmaf(a[u], b.x, acc[0]);
            acc[1] = fmaf(a[u], b.y, acc[1]);
            acc[2] = fmaf(a[u], b.z, acc[2]);
            acc[3] = fmaf(a[u], b.w, acc[3]);
        }
    }
    ushort4 o;
    o.x = f2bf(acc[0]); o.y = f2bf(acc[1]); o.z = f2bf(acc[2]); o.w = f2bf(acc[3]);
    *(ushort4*)(xf + (size_t)(n0 + r) * 128 + c0) = o;
}

// ---------------------------------------------------------------------------
// MFMA stage helper: wave computes two 16-col tiles t0,t1.
__device__ __forceinline__ void mfma_stage2(const short* A_lds, const short* wp,
                                            int lane, int t0, int t1,
                                            f32x4& acc0, f32x4& acc1) {
    const int m = lane & 15, q = lane >> 4;
    #pragma unroll
    for (int ks = 0; ks < 4; ++ks) {
        short8_t a  = *(const short8_t*)(A_lds + m * 136 + ks * 32 + q * 8);
        short8_t b0 = *(const short8_t*)(wp + (t0 * 4 + ks) * 512 + lane * 8);
        short8_t b1 = *(const short8_t*)(wp + (t1 * 4 + ks) * 512 + lane * 8);
        acc0 = __builtin_amdgcn_mfma_f32_16x16x32_bf16(a, b0, acc0, 0, 0, 0);
        acc1 = __builtin_amdgcn_mfma_f32_16x16x32_bf16(a, b1, acc1, 0, 0, 0);
    }
}

// ---------------------------------------------------------------------------
// Fused MFMA layer kernel: 16 nodes/block, 256 threads (4 waves).
// phase A: QUARTER-WAVE edge streams — 16 lanes x 8 cols = one 16B/lane load
//          per row; one wave instr serves 4 edges (4 indep streams/wave).
// MFMA stages: wave wv computes col-tiles wv*2, wv*2+1.
template <bool LAST>
__global__ __launch_bounds__(256) void layer_kernel(const int* __restrict__ offs,
                                                    const int* __restrict__ meta,
                                                    const ushort_t* __restrict__ xf,
                                                    const ushort_t* __restrict__ tabB,
                                                    const short* __restrict__ w2p,
                                                    const float* __restrict__ lin2_b,
                                                    const short* __restrict__ wlp,
                                                    const float* __restrict__ lin_b,
                                                    const short* __restrict__ w1p,
                                                    float* __restrict__ h,
                                                    ushort_t* __restrict__ xf_out,
                                                    const short* __restrict__ o1p,
                                                    const float* __restrict__ o1b,
                                                    const short* __restrict__ o2p,
                                                    const float* __restrict__ o2b,
                                                    float* __restrict__ gs) {
    __shared__ short A1[16 * 136];   // bf16, row stride 136 shorts (272 B)
    __shared__ short A2[16 * 136];
    __shared__ float red[4][64];
    const int tid = threadIdx.x;
    const int n0 = blockIdx.x * 16;
    const int wv = tid >> 6;         // 0..3
    const int lane = tid & 63;

    // ---- phase A: quarter-wave edge streams, nearest table row ----
    {
        const int qt = lane >> 4;        // 0..3
        const int c8 = (lane & 15) * 8;  // 8 cols/lane
        const int node = n0 + wv * 4 + qt;
        int e   = offs[node];
        int end = offs[node + 1];

        float accA[8] = {0.f, 0.f, 0.f, 0.f, 0.f, 0.f, 0.f, 0.f};
        float accB[8] = {0.f, 0.f, 0.f, 0.f, 0.f, 0.f, 0.f, 0.f};

        for (; e + 8 <= end; e += 8) {
            int m[8];
            #pragma unroll
            for (int u = 0; u < 8; ++u) m[u] = meta[e + u];
            short8_t xv[8], tv[8];
            #pragma unroll
            for (int u = 0; u < 8; ++u) {
                xv[u] = *(const short8_t*)(xf + (size_t)(m[u] & 0x3FFF) * 128 + c8);
                tv[u] = *(const short8_t*)(tabB + (size_t)((unsigned)m[u] >> 14) * 128 + c8);
            }
            #pragma unroll
            for (int u = 0; u < 8; ++u)
                nacc8(xv[u], tv[u], (u & 1) ? accB : accA);
        }
        for (; e + 4 <= end; e += 4) {
            int m[4];
            #pragma unroll
            for (int u = 0; u < 4; ++u) m[u] = meta[e + u];
            short8_t xv[4], tv[4];
            #pragma unroll
            for (int u = 0; u < 4; ++u) {
                xv[u] = *(const short8_t*)(xf + (size_t)(m[u] & 0x3FFF) * 128 + c8);
                tv[u] = *(const short8_t*)(tabB + (size_t)((unsigned)m[u] >> 14) * 128 + c8);
            }
            #pragma unroll
            for (int u = 0; u < 4; ++u)
                nacc8(xv[u], tv[u], (u & 1) ? accB : accA);
        }
        for (; e < end; ++e) {
            int mm = meta[e];
            short8_t xv = *(const short8_t*)(xf + (size_t)(mm & 0x3FFF) * 128 + c8);
            short8_t tv = *(const short8_t*)(tabB + (size_t)((unsigned)mm >> 14) * 128 + c8);
            nacc8(xv, tv, accA);
        }

        short8_t out;
        #pragma unroll
        for (int j = 0; j < 8; ++j) out[j] = (short)f2bf(accA[j] + accB[j]);
        *(short8_t*)&A1[(wv * 4 + qt) * 136 + c8] = out;
    }
    __syncthreads();

    const int m = lane & 15, q = lane >> 4;
    const int t0 = wv * 2, t1 = wv * 2 + 1;

    // ---- stage 1: t = ssp(agg @ lin2_w + lin2_b) -> A2 ----
    {
        f32x4 acc0 = {0.f, 0.f, 0.f, 0.f}, acc1 = {0.f, 0.f, 0.f, 0.f};
        mfma_stage2(A1, w2p, lane, t0, t1, acc0, acc1);
        float bv0 = lin2_b[t0 * 16 + m];
        float bv1 = lin2_b[t1 * 16 + m];
        #pragma unroll
        for (int i = 0; i < 4; ++i) {
            int r = q * 4 + i;
            A2[r * 136 + t0 * 16 + m] = (short)f2bf(ssp_f(acc0[i] + bv0));
            A2[r * 136 + t1 * 16 + m] = (short)f2bf(ssp_f(acc1[i] + bv1));
        }
    }
    __syncthreads();

    // ---- stage 2: h_new = h + t @ lin_w + lin_b -> A1 (+ global h if !LAST) ----
    {
        f32x4 acc0 = {0.f, 0.f, 0.f, 0.f}, acc1 = {0.f, 0.f, 0.f, 0.f};
        mfma_stage2(A2, wlp, lane, t0, t1, acc0, acc1);
        float bv0 = lin_b[t0 * 16 + m];
        float bv1 = lin_b[t1 * 16 + m];
        #pragma unroll
        for (int i = 0; i < 4; ++i) {
            int r = q * 4 + i;
            int grow = n0 + r;
            float h0 = h[(size_t)grow * 128 + t0 * 16 + m];
            float h1 = h[(size_t)grow * 128 + t1 * 16 + m];
            float hn0 = h0 + acc0[i] + bv0;
            float hn1 = h1 + acc1[i] + bv1;
            if (!LAST) {
                h[(size_t)grow * 128 + t0 * 16 + m] = hn0;
                h[(size_t)grow * 128 + t1 * 16 + m] = hn1;
            }
            A1[r * 136 + t0 * 16 + m] = (short)f2bf(hn0);
            A1[r * 136 + t1 * 16 + m] = (short)f2bf(hn1);
        }
    }
    __syncthreads();

    if constexpr (!LAST) {
        // ---- stage 3: xf_out = bf16(h_new @ lin1_next) ----
        f32x4 acc0 = {0.f, 0.f, 0.f, 0.f}, acc1 = {0.f, 0.f, 0.f, 0.f};
        mfma_stage2(A1, w1p, lane, t0, t1, acc0, acc1);
        #pragma unroll
        for (int i = 0; i < 4; ++i) {
            int r = q * 4 + i;
            int grow = n0 + r;
            xf_out[(size_t)grow * 128 + t0 * 16 + m] = f2bf(acc0[i]);
            xf_out[(size_t)grow * 128 + t1 * 16 + m] = f2bf(acc1[i]);
        }
    } else {
        // ---- fused head: t1 = ssp(h_new@o1w+o1b); t2 = t1@o2w+o2b; colsum ----
        {
            f32x4 acc = {0.f, 0.f, 0.f, 0.f};
            #pragma unroll
            for (int ks = 0; ks < 4; ++ks) {
                short8_t a = *(const short8_t*)(A1 + m * 136 + ks * 32 + q * 8);
                short8_t b = *(const short8_t*)(o1p + (wv * 4 + ks) * 512 + lane * 8);
                acc = __builtin_amdgcn_mfma_f32_16x16x32_bf16(a, b, acc, 0, 0, 0);
            }
            float bv = o1b[wv * 16 + m];
            #pragma unroll
            for (int i = 0; i < 4; ++i) {
                int r = q * 4 + i;
                A2[r * 136 + wv * 16 + m] = (short)f2bf(ssp_f(acc[i] + bv));
            }
        }
        __syncthreads();
        {
            f32x4 acc = {0.f, 0.f, 0.f, 0.f};
            #pragma unroll
            for (int ks = 0; ks < 2; ++ks) {
                short8_t a = *(const short8_t*)(A2 + m * 136 + ks * 32 + q * 8);
                short8_t b = *(const short8_t*)(o2p + (wv * 2 + ks) * 512 + lane * 8);
                acc = __builtin_amdgcn_mfma_f32_16x16x32_bf16(a, b, acc, 0, 0, 0);
            }
            float bv = o2b[wv * 16 + m];
            float part = acc[0] + acc[1] + acc[2] + acc[3] + 4.0f * bv;
            red[q][wv * 16 + m] = part;
        }
        __syncthreads();
        if (tid < 64) {
            float s = red[0][tid] + red[1][tid] + red[2][tid] + red[3][tid];
            atomicAdd(&gs[tid], s);
        }
    }
}

// out[i] = ro_b[i] + sum_k gs[k] * ro_w[k][i]
__global__ void final_kernel(const float* __restrict__ gs,
                             const float* __restrict__ ro_w,
                             const float* __restrict__ ro_b,
                             float* __restrict__ out) {
    int i = threadIdx.x;
    if (i < 12) {
        float s = ro_b[i];
        for (int k = 0; k < 64; ++k) s = fmaf(gs[k], ro_w[k * 12 + i], s);
        out[i] = s;
    }
}

// ---------------------------------------------------------------------------
extern "C" void kernel_launch(void* const* d_in, const int* in_sizes, int n_in,
                              void* d_out, int out_size, void* d_ws, size_t ws_size,
                              hipStream_t stream) {
    const int*   x      = (const int*)d_in[0];
    const int*   ei     = (const int*)d_in[1];
    const float* dist   = (const float*)d_in[2];
    const float* emb    = (const float*)d_in[3];
    const float* mlp_w1 = (const float*)d_in[4];
    const float* mlp_b1 = (const float*)d_in[5];
    const float* mlp_w2 = (const float*)d_in[6];
    const float* mlp_b2 = (const float*)d_in[7];
    const float* lin1_w = (const float*)d_in[8];
    const float* lin2_w = (const float*)d_in[9];
    const float* lin2_b = (const float*)d_in[10];
    const float* lin_w  = (const float*)d_in[11];
    const float* lin_b  = (const float*)d_in[12];
    const float* out1_w = (const float*)d_in[13];
    const float* out1_b = (const float*)d_in[14];
    const float* out2_w = (const float*)d_in[15];
    const float* out2_b = (const float*)d_in[16];
    const float* ro_w   = (const float*)d_in[17];
    const float* ro_b   = (const float*)d_in[18];
    float* out = (float*)d_out;

    // workspace layout
    char* base = (char*)d_ws;
    float*    h     = (float*)base;     base += (size_t)N_NUM * 128 * 4;
    ushort_t* tabB  = (ushort_t*)base;  base += (size_t)6 * TAB * 128 * 2;
    ushort_t* xf0   = (ushort_t*)base;  base += (size_t)N_NUM * 128 * 2;
    ushort_t* xf1   = (ushort_t*)base;  base += (size_t)N_NUM * 128 * 2;
    int*      meta  = (int*)base;       base += (size_t)E_NUM * 4;
    short*    wpack = (short*)base;     base += (size_t)WP_TOT * 2;
    float*    gs    = (float*)base;     base += 64 * 4;
    int*      offs  = (int*)base;       base += (N_NUM + 1) * 4;
    int*      cursor= (int*)base;       base += N_NUM * 4;
    int*      counts= (int*)base;       base += N_NUM * 4;

    hipMemsetAsync(counts, 0, N_NUM * sizeof(int), stream);
    hipMemsetAsync(gs, 0, 64 * sizeof(float), stream);

    // sort edges by dst (once; dst constant across layers)
    hist_kernel<<<(E_NUM + 255) / 256, 256, 0, stream>>>(ei, counts);
    scan_kernel<<<1, 256, 0, stream>>>(counts, offs, cursor);
    scatter_kernel<<<(E_NUM + 255) / 256, 256, 0, stream>>>(ei, dist, cursor, meta);

    // pack all weights (MFMA B-frag bf16), then build filter tables via MFMA
    pack_kernel<<<(WP_TOT + 255) / 256, 256, 0, stream>>>(
        lin2_w, lin_w, lin1_w, out1_w, out2_w, mlp_w1, mlp_w2, wpack);
    table_kernel<<<6 * (TAB / 16), 512, 0, stream>>>(
        wpack + WP_W1T, mlp_b1, wpack + WP_W2T, mlp_b2, tabB);

    // layer 0 front: h = emb[x], xf0 = bf16(h @ lin1_w[0])
    embed_lin1_kernel<<<NB8, 256, 0, stream>>>(x, emb, lin1_w, h, xf0);

    const short* o1p = wpack + WP_O1;
    const short* o2p = wpack + WP_O2;

    for (int l = 0; l < 6; ++l) {
        ushort_t* xin  = (l & 1) ? xf1 : xf0;
        ushort_t* xout = (l & 1) ? xf0 : xf1;
        const ushort_t* tl = tabB + (size_t)l * TAB * 128;
        const short* w2p = wpack + l * 16384;
        const short* wlp = wpack + (6 + l) * 16384;
        if (l < 5) {
            const short* w1p = wpack + (12 + l + 1) * 16384;   // lin1_w[l+1]
            layer_kernel<false><<<NB16, 256, 0, stream>>>(
                offs, meta, xin, tl,
                w2p, lin2_b + l * 128, wlp, lin_b + l * 128, w1p,
                h, xout, nullptr, nullptr, nullptr, nullptr, nullptr);
        } else {
            layer_kernel<true><<<NB16, 256, 0, stream>>>(
                offs, meta, xin, tl,
                w2p, lin2_b + l * 128, wlp, lin_b + l * 128, nullptr,
                h, nullptr, o1p, out1_b, o2p, out2_b, gs);
        }
    }

    final_kernel<<<1, 64, 0, stream>>>(gs, ro_w, ro_b, out);
}